// Round 5
// baseline (675.049 us; speedup 1.0000x reference)
//
#include <hip/hip_runtime.h>
#include <hip/hip_bf16.h>

typedef __attribute__((ext_vector_type(8))) short short8;
typedef __attribute__((ext_vector_type(4))) float f32x4;
typedef __attribute__((ext_vector_type(16))) float f32x16;

#define WS_B0_OFFSET  18874368u   // b0 after Wt2 (9*1024*1024 bf16)

// -------- Phase 0a: W[d][i][o] fp32 -> Wt2[(d*128+q)][o][j] bf16 (i = q*8+j) --------
__global__ void wt2_kernel(const float* __restrict__ W, short* __restrict__ Wt2) {
    int bid = blockIdx.x;            // 0..1151
    int d = bid >> 7, q = bid & 127;
    int t = threadIdx.x;             // 256
    const float* src = W + (size_t)d * 1048576 + (size_t)q * 8 * 1024;
    short* dst = Wt2 + ((size_t)(d * 128 + q) << 13);
#pragma unroll
    for (int u = 0; u < 4; u++) {
        int o = u * 256 + t;
        short8 v;
#pragma unroll
        for (int j = 0; j < 8; j++)
            v[j] = (short)__bfloat16_as_ushort(__float2bfloat16(src[(size_t)j * 1024 + o]));
        *(short8*)(dst + (size_t)o * 8) = v;
    }
}

// -------- Phase 0b: b0[o] = sum_i W[0][i][o], two-stage --------
__global__ void colsum1(const float* __restrict__ W, float* __restrict__ part) {
    int s = blockIdx.x >> 2;
    int o = (blockIdx.x & 3) * 256 + threadIdx.x;
    const float* p = W + (size_t)s * 32 * 1024 + o;
    float acc = 0.f;
#pragma unroll
    for (int i = 0; i < 32; i++) acc += p[(size_t)i * 1024];
    part[s * 1024 + o] = acc;
}
__global__ void colsum2(const float* __restrict__ part, float* __restrict__ b0) {
    int o = blockIdx.x * 256 + threadIdx.x;
    float acc = 0.f;
#pragma unroll
    for (int s = 0; s < 32; s++) acc += part[s * 1024 + o];
    b0[o] = acc;
}

__device__ __forceinline__ float fast_tanh(float t) {
    float e = __expf(t + t);
    return 1.0f - 2.0f * __builtin_amdgcn_rcpf(e + 1.0f);
}

// -------- Phase 1: fused tanh + Chebyshev + GEMM, producer/consumer waves --------
// 768 thr = 12 waves. Producers = wid%3==0 (4 waves): per-thread 16-elem fp32
// recurrence for the 128x32 A-tile, bf16 ds_write into double-buffered A LDS.
// Consumers (8 waves): wave-tile 64x32, pure {B-load from L2, ds_read A, 4 MFMA}.
// Tile 128x128, grid 512; tn=bid&7 pins one 2.1MB B panel per XCD L2.
extern "C" __global__ void __launch_bounds__(768, 3)
cheby_gemm(const float* __restrict__ x, const short* __restrict__ Wt2,
           const float* __restrict__ b0v, const float* __restrict__ scp,
           const float* __restrict__ bip, float* __restrict__ out) {
    __shared__ __align__(16) char lds[16384];   // A double buffer: 2 x 8KB

    const int tid = threadIdx.x, lane = tid & 63, wid = tid >> 6;
    const int grp = wid / 3, rol = wid - grp * 3;
    const bool isprod = (rol == 0);             // wids 0,3,6,9 -> one per SIMD
    const int tn = blockIdx.x & 7, tm = blockIdx.x >> 3;
    const int m0 = tm << 7, n0 = tn << 7;
    const float sc = scp[0], bi = bip[0];
    const char* wtb = (const char*)Wt2;

    // ---- producer constants: thread owns row=ptid>>1, chunks {ac2, ac2+1} ----
    const int ptid = grp * 64 + lane;           // 0..255
    const int arow = ptid >> 1, ac2 = (ptid & 1) << 1;
    int wbyte[2];
#pragma unroll
    for (int h = 0; h < 2; h++) {
        int c = ac2 + h;
        wbyte[h] = c * 2048 + ((arow ^ (c << 1)) << 4);
    }
    const float* xptr = x + (size_t)(m0 + arow) * 1024 + ac2 * 8;

    // ---- consumer constants: ci in 0..7, wave-tile 64 rows x 32 cols ----
    const int ci = isprod ? 0 : (grp * 2 + rol - 1);
    const int wr = ci >> 2, wc = ci & 3;
    int abase[2], bofs[2];
#pragma unroll
    for (int kh = 0; kh < 2; kh++) {
        int c = kh * 2 + (lane >> 5);
        abase[kh] = c * 2048 + (((wr * 64 + (lane & 31)) ^ (c << 1)) << 4);
        bofs[kh]  = c * 16384 + (n0 + wc * 32 + (lane & 31)) * 16;
    }

    float x2[16], tA[16], tB[16];
    f32x4 xv[4];
    short8 bfA[2], bfB[2];
    f32x16 acc[2];

    auto loadx = [&](int icc) {
#pragma unroll
        for (int q = 0; q < 4; q++)
            xv[q] = *(const f32x4*)(xptr + (icc << 5) + q * 4);
    };
    auto dotanh = [&]() {
#pragma unroll
        for (int q = 0; q < 4; q++)
#pragma unroll
            for (int e = 0; e < 4; e++) {
                float t = fast_tanh(fmaf(xv[q][e], sc, bi));
                tA[q * 4 + e] = t;
                x2[q * 4 + e] = t + t;
            }
    };
    auto writeA = [&](const float* t, int wbuf) {
#pragma unroll
        for (int h = 0; h < 2; h++) {
            short8 v;
#pragma unroll
            for (int j = 0; j < 8; j++)
                v[j] = (short)__bfloat16_as_ushort(__float2bfloat16(t[h * 8 + j]));
            *(short8*)(lds + wbuf * 8192 + wbyte[h]) = v;
        }
    };
    auto bld = [&](short8* bf, int dd, int icc) {
        const char* p = wtb + ((size_t)(dd * 128 + icc * 4) << 14);
#pragma unroll
        for (int kh = 0; kh < 2; kh++)
            bf[kh] = *(const short8*)(p + bofs[kh]);
    };
    auto domfma = [&](int abuf, const short8* bf) {
        short8 af[2][2];
#pragma unroll
        for (int m = 0; m < 2; m++)
#pragma unroll
            for (int kh = 0; kh < 2; kh++)
                af[m][kh] = *(const short8*)(lds + abuf * 8192 + abase[kh] + m * 512);
        __builtin_amdgcn_s_setprio(1);
#pragma unroll
        for (int m = 0; m < 2; m++)
#pragma unroll
            for (int kh = 0; kh < 2; kh++)
                acc[m] = __builtin_amdgcn_mfma_f32_32x32x16_bf16(af[m][kh], bf[kh], acc[m], 0, 0, 0);
        __builtin_amdgcn_s_setprio(0);
    };

#define STEP_END                                                  \
    __builtin_amdgcn_sched_barrier(0);                            \
    asm volatile("s_waitcnt lgkmcnt(0)" ::: "memory");            \
    __builtin_amdgcn_s_barrier();                                 \
    __builtin_amdgcn_sched_barrier(0);

    // ---- prologue ----
    if (isprod) {
        loadx(0);
        dotanh();                 // tA = T1, x2 = 2*T1
        writeA(tA, 0);
    } else {
        float v = b0v[n0 + wc * 32 + (lane & 31)];   // degree-0 folded in
        f32x16 a;
#pragma unroll
        for (int r = 0; r < 16; r++) a[r] = v;
        acc[0] = a; acc[1] = a;
        bld(bfA, 1, 0);
    }
    STEP_END

    for (int ic = 0; ic < 32; ++ic) {
        const int icn = ic < 31 ? ic + 1 : 31;
        { // s=0 (d=1): prod T2->tB->buf1
            if (isprod) {
#pragma unroll
                for (int j = 0; j < 16; j++) tB[j] = fmaf(x2[j], tA[j], -1.0f);
                writeA(tB, 1);
            } else { bld(bfB, 2, ic); domfma(0, bfA); }
            STEP_END
        }
        { // s=1 (d=2): prod T3->tA->buf0
            if (isprod) {
#pragma unroll
                for (int j = 0; j < 16; j++) tA[j] = fmaf(x2[j], tB[j], -tA[j]);
                writeA(tA, 0);
            } else { bld(bfA, 3, ic); domfma(1, bfB); }
            STEP_END
        }
        { // s=2 (d=3): prod T4->tB->buf1
            if (isprod) {
#pragma unroll
                for (int j = 0; j < 16; j++) tB[j] = fmaf(x2[j], tA[j], -tB[j]);
                writeA(tB, 1);
            } else { bld(bfB, 4, ic); domfma(0, bfA); }
            STEP_END
        }
        { // s=3 (d=4): prod T5->tA->buf0
            if (isprod) {
#pragma unroll
                for (int j = 0; j < 16; j++) tA[j] = fmaf(x2[j], tB[j], -tA[j]);
                writeA(tA, 0);
            } else { bld(bfA, 5, ic); domfma(1, bfB); }
            STEP_END
        }
        { // s=4 (d=5): prod T6->tB->buf1
            if (isprod) {
#pragma unroll
                for (int j = 0; j < 16; j++) tB[j] = fmaf(x2[j], tA[j], -tB[j]);
                writeA(tB, 1);
            } else { bld(bfB, 6, ic); domfma(0, bfA); }
            STEP_END
        }
        { // s=5 (d=6): prod T7->tA->buf0; prefetch next x
            if (isprod) {
                loadx(icn);
#pragma unroll
                for (int j = 0; j < 16; j++) tA[j] = fmaf(x2[j], tB[j], -tA[j]);
                writeA(tA, 0);
            } else { bld(bfA, 7, ic); domfma(1, bfB); }
            STEP_END
        }
        { // s=6 (d=7): prod T8->tB->buf1
            if (isprod) {
#pragma unroll
                for (int j = 0; j < 16; j++) tB[j] = fmaf(x2[j], tA[j], -tB[j]);
                writeA(tB, 1);
            } else { bld(bfB, 8, ic); domfma(0, bfA); }
            STEP_END
        }
        { // s=7 (d=8): prod tanh(next x) -> T1'->buf0
            if (isprod) {
                dotanh();
                writeA(tA, 0);
            } else { bld(bfA, 1, icn); domfma(1, bfB); }
            STEP_END
        }
    }
#undef STEP_END

    // ---- epilogue (consumers): C/D col=lane&31, row=(r&3)+8*(r>>2)+4*(lane>>5) ----
    if (!isprod) {
#pragma unroll
        for (int m = 0; m < 2; m++) {
            int rbase = m0 + wr * 64 + m * 32 + ((lane >> 5) << 2);
            int colg  = n0 + wc * 32 + (lane & 31);
#pragma unroll
            for (int r = 0; r < 16; r++) {
                int rowg = rbase + (r & 3) + 8 * (r >> 2);
                out[(size_t)rowg * 1024 + colg] = acc[m][r];
            }
        }
    }
}

extern "C" void kernel_launch(void* const* d_in, const int* in_sizes, int n_in,
                              void* d_out, int out_size, void* d_ws, size_t ws_size,
                              hipStream_t stream) {
    const float* x  = (const float*)d_in[0];
    const float* W  = (const float*)d_in[1];
    const float* sc = (const float*)d_in[2];
    const float* bi = (const float*)d_in[3];
    float* out = (float*)d_out;

    short* Wt2 = (short*)d_ws;
    float* b0  = (float*)((char*)d_ws + WS_B0_OFFSET);
    float* part = out;   // colsum partials staged in d_out (fully overwritten by gemm)

    hipLaunchKernelGGL(wt2_kernel, dim3(9 * 128), dim3(256), 0, stream, W, Wt2);
    hipLaunchKernelGGL(colsum1, dim3(128), dim3(256), 0, stream, W, part);
    hipLaunchKernelGGL(colsum2, dim3(4), dim3(256), 0, stream, part, b0);
    hipLaunchKernelGGL(cheby_gemm, dim3(512), dim3(768), 0, stream, x, Wt2, b0, sc, bi, out);
}

// Round 6
// 209.228 us; speedup vs baseline: 3.2264x; 3.2264x over previous
//
#include <hip/hip_runtime.h>
#include <hip/hip_bf16.h>

typedef __attribute__((ext_vector_type(8))) short short8;
typedef __attribute__((ext_vector_type(4))) float f32x4;
typedef __attribute__((ext_vector_type(16))) float f32x16;

#define WS_B0_OFFSET  18874368u   // b0 after Wt2 (9*1024*1024 bf16)

// -------- Phase 0a: W[d][i][o] fp32 -> Wt2[(d*128+q)][o][j] bf16 (i = q*8+j) --------
__global__ void wt2_kernel(const float* __restrict__ W, short* __restrict__ Wt2) {
    int bid = blockIdx.x;            // 0..1151
    int d = bid >> 7, q = bid & 127;
    int t = threadIdx.x;             // 256
    const float* src = W + (size_t)d * 1048576 + (size_t)q * 8 * 1024;
    short* dst = Wt2 + ((size_t)(d * 128 + q) << 13);
#pragma unroll
    for (int u = 0; u < 4; u++) {
        int o = u * 256 + t;
        short8 v;
#pragma unroll
        for (int j = 0; j < 8; j++)
            v[j] = (short)__bfloat16_as_ushort(__float2bfloat16(src[(size_t)j * 1024 + o]));
        *(short8*)(dst + (size_t)o * 8) = v;
    }
}

// -------- Phase 0b: b0[o] = sum_i W[0][i][o], two-stage --------
__global__ void colsum1(const float* __restrict__ W, float* __restrict__ part) {
    int s = blockIdx.x >> 2;
    int o = (blockIdx.x & 3) * 256 + threadIdx.x;
    const float* p = W + (size_t)s * 32 * 1024 + o;
    float acc = 0.f;
#pragma unroll
    for (int i = 0; i < 32; i++) acc += p[(size_t)i * 1024];
    part[s * 1024 + o] = acc;
}
__global__ void colsum2(const float* __restrict__ part, float* __restrict__ b0) {
    int o = blockIdx.x * 256 + threadIdx.x;
    float acc = 0.f;
#pragma unroll
    for (int s = 0; s < 32; s++) acc += part[s * 1024 + o];
    b0[o] = acc;
}

__device__ __forceinline__ float fast_tanh(float t) {
    float e = __expf(t + t);
    return 1.0f - 2.0f * __builtin_amdgcn_rcpf(e + 1.0f);
}

// -------- Phase 1: fused tanh + Chebyshev + GEMM --------
// 512 thr = 8 waves: wr = wid>>1 (32-row slice), wc = wid&1 (64-col slice).
// Tile 128x128, BK=32, grid 512 = 2 blocks/CU (phase-shifted overlap).
// Wave = 32x64: 4 x mfma_32x32x16 per step, acc = 2 x f32x16 (32 AGPR).
// A (bf16 T_d, 128x32) double-buffered LDS; B direct global->reg (XCD-L2
// resident), ping-pong one degree ahead. Per-thread 8-elem fp32 recurrence.
extern "C" __global__ void __launch_bounds__(512, 4)
cheby_gemm(const float* __restrict__ x, const short* __restrict__ Wt2,
           const float* __restrict__ b0v, const float* __restrict__ scp,
           const float* __restrict__ bip, float* __restrict__ out) {
    __shared__ __align__(16) char lds[16384];   // A double buffer: 2 x 8KB

    const int tid = threadIdx.x, lane = tid & 63, wid = tid >> 6;
    const int wr = wid >> 1, wc = wid & 1;
    const int tn = blockIdx.x & 7, tm = blockIdx.x >> 3;  // pair (b, b+256): same tn
    const int m0 = tm << 7, n0 = tn << 7;
    const float sc = scp[0], bi = bip[0];
    const char* wtb = (const char*)Wt2;

    // A ownership: row = tid>>2, chunk ac = tid&3 (8 k-elems)
    const int arow = tid >> 2, ac = tid & 3;
    const int wbyte0 = ac * 2048 + ((arow ^ (ac << 1)) << 4);
    const float* xptr = x + (size_t)(m0 + arow) * 1024 + ac * 8;

    // A-frag read base: chunk c = kh*2 + (lane>>5), row rr = wr*32 + (lane&31)
    int abase[2];
#pragma unroll
    for (int kh = 0; kh < 2; kh++) {
        int c = kh * 2 + (lane >> 5);
        abase[kh] = c * 2048 + (((wr * 32 + (lane & 31)) ^ (c << 1)) << 4);
    }
    // B byte offsets: addr = (d*128 + ic*4 + c)*16384 + o*16
    int bofs[2][2];
#pragma unroll
    for (int n = 0; n < 2; n++)
#pragma unroll
        for (int kh = 0; kh < 2; kh++) {
            int c = kh * 2 + (lane >> 5);
            bofs[n][kh] = (c << 14) + (n0 + wc * 64 + n * 32 + (lane & 31)) * 16;
        }

    auto bld = [&](short8 bf[2][2], int dd, int icc) {
        const char* p = wtb + ((size_t)(dd * 128 + icc * 4) << 14);
#pragma unroll
        for (int n = 0; n < 2; n++)
#pragma unroll
            for (int kh = 0; kh < 2; kh++)
                bf[n][kh] = *(const short8*)(p + bofs[n][kh]);
    };

    f32x4 xv0, xv1;
    auto loadx = [&](int icc) {
        const float* p = xptr + (icc << 5);
        xv0 = *(const f32x4*)p;
        xv1 = *(const f32x4*)(p + 4);
    };

    float x2[8], tA[8], tB[8];
    auto dotanh = [&]() {
#pragma unroll
        for (int j = 0; j < 4; j++) {
            tA[j]     = fast_tanh(fmaf(xv0[j], sc, bi));
            tA[j + 4] = fast_tanh(fmaf(xv1[j], sc, bi));
        }
#pragma unroll
        for (int j = 0; j < 8; j++) x2[j] = tA[j] + tA[j];
    };
    auto writeA = [&](const float* t, int wbuf) {
        short8 v;
#pragma unroll
        for (int j = 0; j < 8; j++)
            v[j] = (short)__bfloat16_as_ushort(__float2bfloat16(t[j]));
        *(short8*)(lds + wbuf * 8192 + wbyte0) = v;
    };

    f32x16 acc[2];
#pragma unroll
    for (int n = 0; n < 2; n++) {
        float v = b0v[n0 + wc * 64 + n * 32 + (lane & 31)];   // degree-0 folded in
        f32x16 a;
#pragma unroll
        for (int r = 0; r < 16; r++) a[r] = v;
        acc[n] = a;
    }

    auto domfma = [&](int abuf, short8 bf[2][2]) {
        short8 af[2];
#pragma unroll
        for (int kh = 0; kh < 2; kh++)
            af[kh] = *(const short8*)(lds + abuf * 8192 + abase[kh]);
        __builtin_amdgcn_s_setprio(1);
#pragma unroll
        for (int n = 0; n < 2; n++)
#pragma unroll
            for (int kh = 0; kh < 2; kh++)
                acc[n] = __builtin_amdgcn_mfma_f32_32x32x16_bf16(af[kh], bf[n][kh], acc[n], 0, 0, 0);
        __builtin_amdgcn_s_setprio(0);
    };

#define STEP_END                                                  \
    __builtin_amdgcn_sched_barrier(0);                            \
    asm volatile("s_waitcnt lgkmcnt(0)" ::: "memory");            \
    __builtin_amdgcn_s_barrier();                                 \
    __builtin_amdgcn_sched_barrier(0);

    short8 bfA[2][2], bfB[2][2];

    // prologue: x(0), B(d=1) -> bfA, tanh -> T1 -> A-buf0
    loadx(0);
    bld(bfA, 1, 0);
    dotanh();
    writeA(tA, 0);
    STEP_END

    for (int ic = 0; ic < 32; ++ic) {
        const int icn = ic < 31 ? ic + 1 : 31;
        { // s=0: use d1/buf0; load d2; T2 = 2t*T1 - 1 -> buf1
            bld(bfB, 2, ic);
#pragma unroll
            for (int j = 0; j < 8; j++) tB[j] = fmaf(x2[j], tA[j], -1.0f);
            writeA(tB, 1);
            domfma(0, bfA);
            STEP_END
        }
        { // s=1: use d2/buf1; load d3; T3 -> buf0
            bld(bfA, 3, ic);
#pragma unroll
            for (int j = 0; j < 8; j++) tA[j] = fmaf(x2[j], tB[j], -tA[j]);
            writeA(tA, 0);
            domfma(1, bfB);
            STEP_END
        }
#define RSTEP(LD, DST, SRC, LBUF, UBUF, RB, WB, XPRE, LIC)        \
        {                                                         \
            bld(LBUF, LD, LIC);                                   \
            if (XPRE) loadx(icn);                                 \
_Pragma("unroll")                                                 \
            for (int j = 0; j < 8; j++)                           \
                DST[j] = fmaf(x2[j], SRC[j], -DST[j]);            \
            writeA(DST, WB);                                      \
            domfma(RB, UBUF);                                     \
            STEP_END                                              \
        }
        RSTEP(4, tB, tA, bfB, bfA, 0, 1, 0, ic)   // s=2: d3, make T4
        RSTEP(5, tA, tB, bfA, bfB, 1, 0, 0, ic)   // s=3: d4, make T5
        RSTEP(6, tB, tA, bfB, bfA, 0, 1, 0, ic)   // s=4: d5, make T6
        RSTEP(7, tA, tB, bfA, bfB, 1, 0, 0, ic)   // s=5: d6, make T7
        RSTEP(8, tB, tA, bfB, bfA, 0, 1, 1, ic)   // s=6: d7, make T8; prefetch x'
#undef RSTEP
        { // s=7: use d8/buf1; load d1(ic+1); tanh(x') -> T1' -> buf0
            bld(bfA, 1, icn);
            dotanh();
            writeA(tA, 0);
            domfma(1, bfB);
            STEP_END
        }
    }
#undef STEP_END

    // epilogue: C/D col=lane&31, row=(r&3)+8*(r>>2)+4*(lane>>5)
    {
        int rbase = m0 + wr * 32 + ((lane >> 5) << 2);
#pragma unroll
        for (int n = 0; n < 2; n++) {
            int colg = n0 + wc * 64 + n * 32 + (lane & 31);
#pragma unroll
            for (int r = 0; r < 16; r++) {
                int rowg = rbase + (r & 3) + 8 * (r >> 2);
                out[(size_t)rowg * 1024 + colg] = acc[n][r];
            }
        }
    }
}

extern "C" void kernel_launch(void* const* d_in, const int* in_sizes, int n_in,
                              void* d_out, int out_size, void* d_ws, size_t ws_size,
                              hipStream_t stream) {
    const float* x  = (const float*)d_in[0];
    const float* W  = (const float*)d_in[1];
    const float* sc = (const float*)d_in[2];
    const float* bi = (const float*)d_in[3];
    float* out = (float*)d_out;

    short* Wt2 = (short*)d_ws;
    float* b0  = (float*)((char*)d_ws + WS_B0_OFFSET);
    float* part = out;   // colsum partials staged in d_out (fully overwritten by gemm)

    hipLaunchKernelGGL(wt2_kernel, dim3(9 * 128), dim3(256), 0, stream, W, Wt2);
    hipLaunchKernelGGL(colsum1, dim3(128), dim3(256), 0, stream, W, part);
    hipLaunchKernelGGL(colsum2, dim3(4), dim3(256), 0, stream, part, b0);
    hipLaunchKernelGGL(cheby_gemm, dim3(512), dim3(512), 0, stream, x, Wt2, b0, sc, bi, out);
}

// Round 7
// 166.919 us; speedup vs baseline: 4.0442x; 1.2535x over previous
//
#include <hip/hip_runtime.h>
#include <hip/hip_bf16.h>

typedef __attribute__((ext_vector_type(8))) short short8;
typedef __attribute__((ext_vector_type(4))) float f32x4;
typedef __attribute__((ext_vector_type(16))) float f32x16;

#define WS_B0_OFFSET  18874368u   // b0 after Wt2 (9*1024*1024 bf16)

// -------- Phase 0a: W[d][i][o] fp32 -> Wt2[(d*128+q)][o][j] bf16 (i = q*8+j) --------
__global__ void wt2_kernel(const float* __restrict__ W, short* __restrict__ Wt2) {
    int bid = blockIdx.x;            // 0..1151
    int d = bid >> 7, q = bid & 127;
    int t = threadIdx.x;             // 256
    const float* src = W + (size_t)d * 1048576 + (size_t)q * 8 * 1024;
    short* dst = Wt2 + ((size_t)(d * 128 + q) << 13);
#pragma unroll
    for (int u = 0; u < 4; u++) {
        int o = u * 256 + t;
        short8 v;
#pragma unroll
        for (int j = 0; j < 8; j++)
            v[j] = (short)__bfloat16_as_ushort(__float2bfloat16(src[(size_t)j * 1024 + o]));
        *(short8*)(dst + (size_t)o * 8) = v;
    }
}

// -------- Phase 0b: b0[o] = sum_i W[0][i][o], two-stage --------
__global__ void colsum1(const float* __restrict__ W, float* __restrict__ part) {
    int s = blockIdx.x >> 2;
    int o = (blockIdx.x & 3) * 256 + threadIdx.x;
    const float* p = W + (size_t)s * 32 * 1024 + o;
    float acc = 0.f;
#pragma unroll
    for (int i = 0; i < 32; i++) acc += p[(size_t)i * 1024];
    part[s * 1024 + o] = acc;
}
__global__ void colsum2(const float* __restrict__ part, float* __restrict__ b0) {
    int o = blockIdx.x * 256 + threadIdx.x;
    float acc = 0.f;
#pragma unroll
    for (int s = 0; s < 32; s++) acc += part[s * 1024 + o];
    b0[o] = acc;
}

__device__ __forceinline__ float fast_tanh(float t) {
    float e = __expf(t + t);
    return 1.0f - 2.0f * __builtin_amdgcn_rcpf(e + 1.0f);
}

// -------- Phase 1: fused tanh + Chebyshev + GEMM --------
// R4 geometry: 512 thr = 8 waves (wc = wid&3 col slice, kh = wid>>2 K-half),
// tile 128x256, BK=32, grid 256 (1 block/CU). NEW: A-fragments register-
// prefetched across the barrier (MFMA burst has no LDS dependency; single
// barrier per step; ds_read latency hidden under next burst).
extern "C" __global__ void __launch_bounds__(512, 2)
cheby_gemm(const float* __restrict__ x, const short* __restrict__ Wt2,
           const float* __restrict__ b0v, const float* __restrict__ scp,
           const float* __restrict__ bip, float* __restrict__ out) {
    __shared__ __align__(16) char lds[49152];   // A: 2x8KB @0; merge 32KB @16384

    const int tid = threadIdx.x, lane = tid & 63, wid = tid >> 6;
    const int wc = wid & 3, kh = wid >> 2;
    const int tn = blockIdx.x & 3, tm = blockIdx.x >> 2;   // bid%8 -> fixed tn per XCD
    const int m0 = tm << 7, n0 = tn << 8;
    const float sc = scp[0], bi = bip[0];
    const char* wtb = (const char*)Wt2;

    // A ownership: row = tid>>2, chunk ac = tid&3 (8 k-elems)
    const int arow = tid >> 2, ac = tid & 3;
    const int wbyte0 = ac * 2048 + ((arow ^ (ac << 1)) << 4);
    const float* xptr = x + (size_t)(m0 + arow) * 1024 + ac * 8;

    // A-frag read base: chunk cfr = kh*2 + (lane>>5), rows m*32 + (lane&31)
    const int cfr = kh * 2 + (lane >> 5);
    const int abase = cfr * 2048 + (((lane & 31) ^ (cfr << 1)) << 4);
    // B byte offsets
    int bofs[2];
#pragma unroll
    for (int n = 0; n < 2; n++)
        bofs[n] = cfr * 16384 + (n0 + wc * 64 + n * 32 + (lane & 31)) * 16;

    auto bld = [&](short8* bf, int dd, int icc) {
        const char* p = wtb + ((size_t)(dd * 128 + icc * 4) << 14);
#pragma unroll
        for (int n = 0; n < 2; n++)
            bf[n] = *(const short8*)(p + bofs[n]);
    };

    f32x4 xv0, xv1;
    auto loadx = [&](int icc) {
        const float* p = xptr + (icc << 5);
        xv0 = *(const f32x4*)p;
        xv1 = *(const f32x4*)(p + 4);
    };

    float x2[8], tA[8], tB[8];
    auto dotanh = [&]() {
#pragma unroll
        for (int j = 0; j < 4; j++) {
            tA[j]     = fast_tanh(fmaf(xv0[j], sc, bi));
            tA[j + 4] = fast_tanh(fmaf(xv1[j], sc, bi));
        }
#pragma unroll
        for (int j = 0; j < 8; j++) x2[j] = tA[j] + tA[j];
    };
    auto writeA = [&](const float* t, int wbuf) {
        short8 v;
#pragma unroll
        for (int j = 0; j < 8; j++)
            v[j] = (short)__bfloat16_as_ushort(__float2bfloat16(t[j]));
        *(short8*)(lds + wbuf * 8192 + wbyte0) = v;
    };
    auto readA = [&](short8* af, int buf) {
#pragma unroll
        for (int m = 0; m < 4; m++)
            af[m] = *(const short8*)(lds + buf * 8192 + abase + m * 512);
    };

    f32x16 acc[4][2];
#pragma unroll
    for (int n = 0; n < 2; n++) {
        float v = (kh == 0) ? b0v[n0 + wc * 64 + n * 32 + (lane & 31)] : 0.0f;
        f32x16 a;
#pragma unroll
        for (int r = 0; r < 16; r++) a[r] = v;
#pragma unroll
        for (int m = 0; m < 4; m++) acc[m][n] = a;
    }

    auto domfma = [&](const short8* af, const short8* bf) {
        __builtin_amdgcn_s_setprio(1);
#pragma unroll
        for (int m = 0; m < 4; m++)
#pragma unroll
            for (int n = 0; n < 2; n++)
                acc[m][n] = __builtin_amdgcn_mfma_f32_32x32x16_bf16(af[m], bf[n], acc[m][n], 0, 0, 0);
        __builtin_amdgcn_s_setprio(0);
    };

    short8 af0[4], af1[4], bfA[2], bfB[2];

#define DRAIN_BAR                                                 \
    __builtin_amdgcn_sched_barrier(0);                            \
    asm volatile("s_waitcnt lgkmcnt(0)" ::: "memory");            \
    __builtin_amdgcn_s_barrier();

    // ---- prologue: T1 -> buf0; B(d=1) -> bfA; prefetch af0 from buf0 ----
    loadx(0);
    bld(bfA, 1, 0);
    dotanh();
    writeA(tA, 0);
    DRAIN_BAR
    readA(af0, 0);
    __builtin_amdgcn_sched_barrier(0);

    // step template: domfma(afU,bfU) | bld(bfL) + recurrence + writeA(WB)
    //                | drain+barrier | readA(afP, WB)
#define RSTEP(AFU, AFP, BFU, BFL, LD, LIC, WB, RECUR, XPRE)       \
    {                                                             \
        domfma(AFU, BFU);                                         \
        __builtin_amdgcn_sched_barrier(0);                        \
        bld(BFL, LD, LIC);                                        \
        if (XPRE) loadx(icn);                                     \
        RECUR                                                     \
        DRAIN_BAR                                                 \
        readA(AFP, WB);                                           \
        __builtin_amdgcn_sched_barrier(0);                        \
    }
#define REC_T2  { for (int j = 0; j < 8; j++) tB[j] = fmaf(x2[j], tA[j], -1.0f);  writeA(tB, 1); }
#define REC_BA(WB) { for (int j = 0; j < 8; j++) tA[j] = fmaf(x2[j], tB[j], -tA[j]); writeA(tA, WB); }
#define REC_AB(WB) { for (int j = 0; j < 8; j++) tB[j] = fmaf(x2[j], tA[j], -tB[j]); writeA(tB, WB); }
#define REC_TANH { dotanh(); writeA(tA, 0); }

    for (int ic = 0; ic < 32; ++ic) {
        const int icn = ic < 31 ? ic + 1 : 31;
        RSTEP(af0, af1, bfA, bfB, 2, ic, 1, REC_T2,     0)  // s0 d=1, make T2
        RSTEP(af1, af0, bfB, bfA, 3, ic, 0, REC_BA(0),  0)  // s1 d=2, make T3
        RSTEP(af0, af1, bfA, bfB, 4, ic, 1, REC_AB(1),  0)  // s2 d=3, make T4
        RSTEP(af1, af0, bfB, bfA, 5, ic, 0, REC_BA(0),  0)  // s3 d=4, make T5
        RSTEP(af0, af1, bfA, bfB, 6, ic, 1, REC_AB(1),  0)  // s4 d=5, make T6
        RSTEP(af1, af0, bfB, bfA, 7, ic, 0, REC_BA(0),  1)  // s5 d=6, make T7; prefetch x'
        RSTEP(af0, af1, bfA, bfB, 8, ic, 1, REC_AB(1),  0)  // s6 d=7, make T8
        RSTEP(af1, af0, bfB, bfA, 1, icn, 0, REC_TANH,  0)  // s7 d=8, make T1'
    }
#undef RSTEP
#undef DRAIN_BAR

    // -------- K-split merge (kh=1 accs added into kh=0 accs), chunked by m --------
#pragma unroll
    for (int m = 0; m < 4; m++) {
        if (kh == 1) {
#pragma unroll
            for (int n = 0; n < 2; n++) {
                char* base = lds + 16384 + (wc * 2 + n) * 4096 + lane * 64;
#pragma unroll
                for (int q = 0; q < 4; q++) {
                    f32x4 v = {acc[m][n][q * 4 + 0], acc[m][n][q * 4 + 1],
                               acc[m][n][q * 4 + 2], acc[m][n][q * 4 + 3]};
                    *(f32x4*)(base + ((q ^ (lane & 3)) << 4)) = v;
                }
            }
        }
        __syncthreads();
        if (kh == 0) {
#pragma unroll
            for (int n = 0; n < 2; n++) {
                const char* base = lds + 16384 + (wc * 2 + n) * 4096 + lane * 64;
#pragma unroll
                for (int q = 0; q < 4; q++) {
                    f32x4 v = *(const f32x4*)(base + ((q ^ (lane & 3)) << 4));
#pragma unroll
                    for (int e = 0; e < 4; e++) acc[m][n][q * 4 + e] += v[e];
                }
            }
        }
        __syncthreads();
    }

    // -------- store (kh=0 waves): C/D col=lane&31, row=(r&3)+8*(r>>2)+4*(lane>>5) --------
    if (kh == 0) {
#pragma unroll
        for (int m = 0; m < 4; m++) {
            int rbase = m0 + m * 32 + ((lane >> 5) << 2);
#pragma unroll
            for (int n = 0; n < 2; n++) {
                int colg = n0 + wc * 64 + n * 32 + (lane & 31);
#pragma unroll
                for (int r = 0; r < 16; r++) {
                    int rowg = rbase + (r & 3) + 8 * (r >> 2);
                    out[(size_t)rowg * 1024 + colg] = acc[m][n][r];
                }
            }
        }
    }
}

extern "C" void kernel_launch(void* const* d_in, const int* in_sizes, int n_in,
                              void* d_out, int out_size, void* d_ws, size_t ws_size,
                              hipStream_t stream) {
    const float* x  = (const float*)d_in[0];
    const float* W  = (const float*)d_in[1];
    const float* sc = (const float*)d_in[2];
    const float* bi = (const float*)d_in[3];
    float* out = (float*)d_out;

    short* Wt2 = (short*)d_ws;
    float* b0  = (float*)((char*)d_ws + WS_B0_OFFSET);
    float* part = out;   // colsum partials staged in d_out (fully overwritten by gemm)

    hipLaunchKernelGGL(wt2_kernel, dim3(9 * 128), dim3(256), 0, stream, W, Wt2);
    hipLaunchKernelGGL(colsum1, dim3(128), dim3(256), 0, stream, W, part);
    hipLaunchKernelGGL(colsum2, dim3(4), dim3(256), 0, stream, part, b0);
    hipLaunchKernelGGL(cheby_gemm, dim3(256), dim3(512), 0, stream, x, Wt2, b0, sc, bi, out);
}